// Round 1
// baseline (1344.208 us; speedup 1.0000x reference)
//
#include <hip/hip_runtime.h>
#include <cstdint>

namespace {

constexpr int LSIDE = 64;   // lattice side
constexpr int HID   = 32;   // hidden size
constexpr int PAD   = 36;   // carry row stride in floats (144B, 16B-aligned)

__global__ __launch_bounds__(64) void rnn2d_kernel(
    const int*   __restrict__ x,     // [B, L, L]
    const float* __restrict__ Win,   // [4, H]
    const float* __restrict__ WcH,   // [H, H]
    const float* __restrict__ WcV,   // [H, H]
    const float* __restrict__ bV,    // [H]
    const float* __restrict__ Wout,  // [H, 2]
    const float* __restrict__ bout,  // [2]
    float*       __restrict__ out)   // [B]
{
    const int bidx = blockIdx.x;
    const int l  = threadIdx.x;     // 0..63
    const int h  = l & 31;          // hidden index
    const int kh = l >> 5;          // k-half (0: k in [0,16), 1: k in [16,32))

    __shared__ float carry[LSIDE * PAD];  // vertical carries, physical-column indexed
    __shared__ float woutS[2 * HID];      // Wout staged for the output pass

    // zero carries (row -1 vertical carry = 0) + stage Wout
    for (int idx = l; idx < LSIDE * PAD; idx += 64) carry[idx] = 0.f;
    woutS[l] = Wout[l];                   // 64 = H*2 values
    const float b0 = bout[0];
    const float b1 = bout[1];

    // per-lane weight registers: column h, k-half rows
    float wch[16], wcv[16], winr[4];
#pragma unroll
    for (int q = 0; q < 16; ++q) {
        wch[q] = WcH[(16 * kh + q) * HID + h];
        wcv[q] = WcV[(16 * kh + q) * HID + h];
    }
#pragma unroll
    for (int m = 0; m < 4; ++m) winr[m] = Win[m * HID + h];
    const float bv = bV[h];

    const int* xb = x + bidx * (LSIDE * LSIDE);
    const int bpbase = (l & 32) << 1;     // byte addr of lane 16*kh for ds_bpermute

    float logp = 0.f;
    unsigned long long xprev = 0ull;

    __syncthreads();  // single wave; cheap safety for LDS init

    for (int row = 0; row < LSIDE; ++row) {
        const int xv = xb[row * LSIDE + l];
        const unsigned long long xcur = __ballot(xv == 1);
        const bool fwd = ((row & 1) == 0);

        float hc[16], cv[16];
#pragma unroll
        for (int q = 0; q < 16; ++q) hc[q] = 0.f;   // hcarry starts at 0 each row
        {   // prefetch vertical carry for s=0 (previous row's value)
            const int p0 = fwd ? 0 : (LSIDE - 1);
            const float4* src = reinterpret_cast<const float4*>(&carry[p0 * PAD + 16 * kh]);
#pragma unroll
            for (int q = 0; q < 4; ++q) {
                const float4 v = src[q];
                cv[4*q+0] = v.x; cv[4*q+1] = v.y; cv[4*q+2] = v.z; cv[4*q+3] = v.w;
            }
        }

        for (int s = 0; s < LSIDE; ++s) {
            const int p = fwd ? s : (LSIDE - 1 - s);   // physical column

            // half-dot: k-half of (cV @ WcV) + (hcarry @ WcH)
            float a0 = 0.f, a1 = 0.f, a2 = 0.f, a3 = 0.f;
#pragma unroll
            for (int q = 0; q < 16; q += 4) {
                a0 = fmaf(cv[q+0], wcv[q+0], a0);
                a1 = fmaf(cv[q+1], wcv[q+1], a1);
                a2 = fmaf(cv[q+2], wcv[q+2], a2);
                a3 = fmaf(cv[q+3], wcv[q+3], a3);
            }
#pragma unroll
            for (int q = 0; q < 16; q += 4) {
                a0 = fmaf(hc[q+0], wch[q+0], a0);
                a1 = fmaf(hc[q+1], wch[q+1], a1);
                a2 = fmaf(hc[q+2], wch[q+2], a2);
                a3 = fmaf(hc[q+3], wch[q+3], a3);
            }
            float part = (a0 + a1) + (a2 + a3);
            part += __shfl_xor(part, 32, 64);          // combine the two k-halves

            // one-hot input terms: row selects from Win via ballot-mask bits
            float wconst = bv;
            if (s > 0) {
                const int pprev = fwd ? (s - 1) : (LSIDE - s);
                const int abit = (int)((xcur >> pprev) & 1ull);
                wconst += abit ? winr[1] : winr[0];
            }
            if (row > 0) {
                const int bbit = (int)((xprev >> p) & 1ull);
                wconst += bbit ? winr[3] : winr[2];
            }
            const float pre  = part + wconst;
            const float newC = (pre > 0.f) ? pre : (__expf(pre) - 1.f);  // elu

            if (l < 32) carry[p * PAD + h] = newC;     // store carry (next row + outputs)

            // prefetch next column's vertical carry (still previous row's value)
            if (s < LSIDE - 1) {
                const int pn = fwd ? (s + 1) : (LSIDE - 2 - s);
                const float4* src = reinterpret_cast<const float4*>(&carry[pn * PAD + 16 * kh]);
#pragma unroll
                for (int q = 0; q < 4; ++q) {
                    const float4 v = src[q];
                    cv[4*q+0] = v.x; cv[4*q+1] = v.y; cv[4*q+2] = v.z; cv[4*q+3] = v.w;
                }
            }

            // replicate newC across lanes -> this lane's k-half of hcarry
            const int nci = __float_as_int(newC);
#pragma unroll
            for (int q = 0; q < 16; ++q)
                hc[q] = __int_as_float(__builtin_amdgcn_ds_bpermute(bpbase + 4 * q, nci));
        }

        // deferred output pass: lane j = l handles physical column j
        {
            float o0 = b0, o1 = b1;
            const float4* crow = reinterpret_cast<const float4*>(&carry[l * PAD]);
#pragma unroll
            for (int q = 0; q < 8; ++q) {
                const float4 c4 = crow[q];
                o0 = fmaf(c4.x, woutS[(4*q+0)*2+0], o0);
                o1 = fmaf(c4.x, woutS[(4*q+0)*2+1], o1);
                o0 = fmaf(c4.y, woutS[(4*q+1)*2+0], o0);
                o1 = fmaf(c4.y, woutS[(4*q+1)*2+1], o1);
                o0 = fmaf(c4.z, woutS[(4*q+2)*2+0], o0);
                o1 = fmaf(c4.z, woutS[(4*q+2)*2+1], o1);
                o0 = fmaf(c4.w, woutS[(4*q+3)*2+0], o0);
                o1 = fmaf(c4.w, woutS[(4*q+3)*2+1], o1);
            }
            const float mx  = fmaxf(o0, o1);
            const float lse = mx + __logf(__expf(o0 - mx) + __expf(o1 - mx));
            const int xbit  = (int)((xcur >> l) & 1ull);
            logp += (xbit ? o1 : o0) - lse;
        }
        xprev = xcur;
    }

    // reduce per-column log-probs across the 64 lanes
    float tot = logp;
#pragma unroll
    for (int off = 32; off >= 1; off >>= 1) tot += __shfl_xor(tot, off, 64);
    if (l == 0) out[bidx] = 0.5f * tot;
}

} // namespace

extern "C" void kernel_launch(void* const* d_in, const int* in_sizes, int n_in,
                              void* d_out, int out_size, void* d_ws, size_t ws_size,
                              hipStream_t stream) {
    (void)n_in; (void)out_size; (void)d_ws; (void)ws_size;
    const int*   x    = (const int*)  d_in[0];
    const float* Win  = (const float*)d_in[1];
    const float* WcH  = (const float*)d_in[2];
    const float* WcV  = (const float*)d_in[3];
    const float* bV   = (const float*)d_in[4];
    const float* Wout = (const float*)d_in[5];
    const float* bout = (const float*)d_in[6];
    float*       out  = (float*)d_out;

    const int B = in_sizes[0] / (LSIDE * LSIDE);
    rnn2d_kernel<<<B, 64, 0, stream>>>(x, Win, WcH, WcV, bV, Wout, bout, out);
}

// Round 3
// 1171.916 us; speedup vs baseline: 1.1470x; 1.1470x over previous
//
#include <hip/hip_runtime.h>
#include <cstdint>

namespace {

typedef _Float16 half_t;
typedef half_t half8  __attribute__((ext_vector_type(8)));
typedef __fp16 fp16x2 __attribute__((ext_vector_type(2)));
typedef float  f32x4  __attribute__((ext_vector_type(4)));

constexpr int LSIDE = 64;   // lattice side
constexpr int HID   = 32;   // hidden size
constexpr int NB    = 16;   // batch elements per wave (MFMA N dim)

__device__ inline half8 as_h8(uint4 u) { return __builtin_bit_cast(half8, u); }
__device__ inline uint4 as_u4(half8 h) { return __builtin_bit_cast(uint4, h); }
__device__ inline unsigned pk2(float a, float b) {
    fp16x2 t = __builtin_amdgcn_cvt_pkrtz(a, b);
    return __builtin_bit_cast(unsigned, t);
}
__device__ inline float elu1(float v) {
    float e = __expf(v) - 1.f;
    return v > 0.f ? v : e;
}

#define MFMA(a, b, c) __builtin_amdgcn_mfma_f32_16x16x32_f16((a), (b), (c), 0, 0, 0)

// Layout conventions (v_mfma_f32_16x16x32_f16):
//   A (16x32): lane holds A[row = l&15][k = 8*(l>>4)+e], e=0..7
//   B (32x16): lane holds B[k = 8*(l>>4)+e][col = l&15]
//   C (16x16): lane holds C[row = 4*(l>>4)+c][col = l&15], c=0..3
// A rows are permuted so C of step s IS the B fragment of step s+1:
//   MFMA1 physical row rho -> logical j1 = 8*(rho>>2) + (rho&3)
//   MFMA2 physical row rho -> logical j2 = j1 + 4
// => lane group gets j = {8g..8g+3} from acc1 regs, {8g+4..8g+7} from acc2 regs
//    = exactly k = 8g+e of the next B fragment.

__global__ __launch_bounds__(64) void rnn2d_mfma(
    const int*   __restrict__ x,     // [B, 64, 64]
    const float* __restrict__ Win,   // [4, 32]
    const float* __restrict__ WcH,   // [32, 32]
    const float* __restrict__ WcV,   // [32, 32]
    const float* __restrict__ bV,    // [32]
    const float* __restrict__ Wout,  // [32, 2]
    const float* __restrict__ bout,  // [2]
    float*       __restrict__ out)   // [B]
{
    const int l = threadIdx.x;
    const int r = l & 15;
    const int g = l >> 4;
    const int n = l & 15;                 // batch-in-wave
    const int bbase = blockIdx.x * NB;

    __shared__ uint4 cvs[LSIDE * 64];     // [col][lane] f16x8 vertical-carry frags

    {   // zero: row -1 vertical carries are 0
        const uint4 z{0u, 0u, 0u, 0u};
        for (int i = l; i < LSIDE * 64; i += 64) cvs[i] = z;
    }

    // ---- constant A fragments ----
    const int j1 = 8 * (r >> 2) + (r & 3);
    const int j2 = j1 + 4;
    half8 A1h, A2h, A1v, A2v, A3a, A3b, Awd;
#pragma unroll
    for (int e = 0; e < 8; ++e) {
        const int k = 8 * g + e;
        A1h[e] = (half_t)WcH[k * HID + j1];
        A2h[e] = (half_t)WcH[k * HID + j2];
        A1v[e] = (half_t)WcV[k * HID + j1];
        A2v[e] = (half_t)WcV[k * HID + j2];
        float a3a = 0.f, a3b = 0.f;
        if (k < 4)       { a3a = Win[k * HID + j1]; a3b = Win[k * HID + j2]; }
        else if (k == 4) { a3a = bV[j1];            a3b = bV[j2]; }
        A3a[e] = (half_t)a3a;
        A3b[e] = (half_t)a3b;
        Awd[e] = (half_t)((r == 0) ? (Wout[k * 2 + 1] - Wout[k * 2 + 0]) : 0.f);
    }
    const float db = bout[1] - bout[0];
    f32x4 dinit; dinit[0] = db; dinit[1] = db; dinit[2] = db; dinit[3] = db;
    f32x4 zc;    zc[0] = 0.f;  zc[1] = 0.f;  zc[2] = 0.f;  zc[3] = 0.f;

    const unsigned gmask   = (g == 0) ? 0xFFFFFFFFu : 0u;
    const unsigned onePair = 0x00003C00u & gmask;      // f16 pair (1.0, 0)

    const int* xw = x + (long)bbase * (LSIDE * LSIDE);

    __syncthreads();

    // ---- row-bitmask machinery (ballot-built, no workspace) ----
    int xr[NB];
#pragma unroll
    for (int nn = 0; nn < NB; ++nn) xr[nn] = xw[nn * (LSIDE * LSIDE) + 0 * LSIDE + l];

    unsigned long long rmask_prev = 0ull, rmask_cur = 0ull;
    float logp = 0.f;

    for (int row = 0; row < LSIDE; ++row) {
        // build this row's masks from prefetched xr
        {
            unsigned long long rm = 0ull;
#pragma unroll
            for (int nn = 0; nn < NB; ++nn) {
                const unsigned long long bal = __ballot(xr[nn] == 1);
                rm = (n == nn) ? bal : rm;
            }
            rmask_cur = rm;
        }
        if (row < LSIDE - 1) {   // prefetch next row's spins
#pragma unroll
            for (int nn = 0; nn < NB; ++nn)
                xr[nn] = xw[nn * (LSIDE * LSIDE) + (row + 1) * LSIDE + l];
        }

        const bool fwd = ((row & 1) == 0);
        const int pstep = fwd ? 1 : -1;
        int p = fwd ? 0 : (LSIDE - 1);
        const unsigned rowm = (row > 0) ? 0xFFFFFFFFu : 0u;

        // state(s=-1) = 0
        uint4 hz{0u, 0u, 0u, 0u};
        half8 hcB = as_h8(hz);

        // pre for s=0: one-hot/bias + vertical carry
        f32x4 pre1, pre2;
        {
            const unsigned bb0 = (unsigned)(rmask_prev >> p) & 1u;
            const unsigned bP  = (bb0 ? 0x3C000000u : 0x00003C00u) & gmask & rowm;
            uint4 b3u{0u, bP, onePair, 0u};           // s=0: no left-neighbor term
            const half8 B3 = as_h8(b3u);
            const half8 cv0 = as_h8(cvs[(p << 6) + l]);
            pre1 = MFMA(A3a, B3, zc);
            pre2 = MFMA(A3b, B3, zc);
            pre1 = MFMA(A1v, cv0, pre1);
            pre2 = MFMA(A2v, cv0, pre2);
        }
        uint4 cvN = cvs[((p + pstep) << 6) + l];      // prefetch cv(1)

        unsigned xb_prev = 0u;

        for (int s = 0; s < LSIDE; ++s) {
            // recurrence MFMAs (chain)
            f32x4 acc1 = MFMA(A1h, hcB, pre1);
            f32x4 acc2 = MFMA(A2h, hcB, pre2);

            // lagged output path + vertical-carry store for step s-1
            if (s > 0) {
                f32x4 od = MFMA(Awd, hcB, dinit);
                const float d  = od[0];
                const float dx = xb_prev ? d : -d;
                logp -= __logf(1.f + __expf(-dx));
                cvs[((p - pstep) << 6) + l] = as_u4(hcB);
            }

            const unsigned xb = (unsigned)(rmask_cur >> p) & 1u;  // spin at (row, p)

            // build next step's pre (off the chain)
            if (s < LSIDE - 1) {
                const int pn = p + pstep;
                const unsigned bbn = (unsigned)(rmask_prev >> pn) & 1u;
                const unsigned aP = (xb  ? 0x3C000000u : 0x00003C00u) & gmask;
                const unsigned bP = (bbn ? 0x3C000000u : 0x00003C00u) & gmask & rowm;
                uint4 b3u{aP, bP, onePair, 0u};
                const half8 B3n = as_h8(b3u);
                f32x4 q1 = MFMA(A3a, B3n, zc);
                f32x4 q2 = MFMA(A3b, B3n, zc);
                const half8 cvh = as_h8(cvN);
                q1 = MFMA(A1v, cvh, q1);
                q2 = MFMA(A2v, cvh, q2);
                pre1 = q1;
                pre2 = q2;
                if (s < LSIDE - 2) cvN = cvs[((p + 2 * pstep) << 6) + l];
            }

            // elu + pack -> new state fragment (== next B operand)
            {
                uint4 nb;
                nb.x = pk2(elu1(acc1[0]), elu1(acc1[1]));
                nb.y = pk2(elu1(acc1[2]), elu1(acc1[3]));
                nb.z = pk2(elu1(acc2[0]), elu1(acc2[1]));
                nb.w = pk2(elu1(acc2[2]), elu1(acc2[3]));
                hcB = as_h8(nb);
            }

            xb_prev = xb;
            p += pstep;
        }

        // epilogue: output + store for s = 63
        {
            f32x4 od = MFMA(Awd, hcB, dinit);
            const float d  = od[0];
            const float dx = xb_prev ? d : -d;
            logp -= __logf(1.f + __expf(-dx));
            cvs[((p - pstep) << 6) + l] = as_u4(hcB);
        }

        rmask_prev = rmask_cur;
    }

    if (l < NB) out[bbase + l] = 0.5f * logp;
}

} // namespace

extern "C" void kernel_launch(void* const* d_in, const int* in_sizes, int n_in,
                              void* d_out, int out_size, void* d_ws, size_t ws_size,
                              hipStream_t stream) {
    (void)n_in; (void)out_size; (void)d_ws; (void)ws_size;
    const int*   x    = (const int*)  d_in[0];
    const float* Win  = (const float*)d_in[1];
    const float* WcH  = (const float*)d_in[2];
    const float* WcV  = (const float*)d_in[3];
    const float* bV   = (const float*)d_in[4];
    const float* Wout = (const float*)d_in[5];
    const float* bout = (const float*)d_in[6];
    float*       out  = (float*)d_out;

    const int B = in_sizes[0] / (LSIDE * LSIDE);
    rnn2d_mfma<<<B / NB, 64, 0, stream>>>(x, Win, WcH, WcV, bV, Wout, bout, out);
}